// Round 1
// baseline (434.299 us; speedup 1.0000x reference)
//
#include <hip/hip_runtime.h>
#include <stdint.h>

#define THREADS 256

// ---------------- bitmask path ----------------

__global__ void zero_mask_kernel(uint32_t* __restrict__ mask, int nwords) {
    int i = blockIdx.x * blockDim.x + threadIdx.x;
    int stride = gridDim.x * blockDim.x;
    for (; i < nwords; i += stride) mask[i] = 0u;
}

__global__ void set_bits_kernel(const int* __restrict__ idx, int k,
                                uint32_t* __restrict__ mask) {
    int i = blockIdx.x * blockDim.x + threadIdx.x;
    int stride = gridDim.x * blockDim.x;
    for (; i < k; i += stride) {
        unsigned v = (unsigned)idx[i];
        atomicOr(&mask[v >> 5], 1u << (v & 31u));
    }
}

__global__ void apply_kernel(const float4* __restrict__ X,
                             const uint32_t* __restrict__ mask,
                             float4* __restrict__ out, int nvec,
                             const float* __restrict__ Xs,
                             float* __restrict__ outs, int nscalar_base,
                             int ntotal) {
    int i = blockIdx.x * blockDim.x + threadIdx.x;
    int stride = gridDim.x * blockDim.x;
    for (int j = i; j < nvec; j += stride) {
        float4 v = X[j];
        unsigned base = (unsigned)j << 2;
        unsigned bits = (mask[base >> 5] >> (base & 31u)) & 0xFu;
        if (bits & 1u) v.x = 0.0f;
        if (bits & 2u) v.y = 0.0f;
        if (bits & 4u) v.z = 0.0f;
        if (bits & 8u) v.w = 0.0f;
        out[j] = v;
    }
    // scalar tail (out_size not divisible by 4) — handled by first few threads
    int t = nscalar_base + i;
    if (t < ntotal) {
        float v = Xs[t];
        unsigned bit = (mask[(unsigned)t >> 5] >> ((unsigned)t & 31u)) & 1u;
        outs[t] = bit ? 0.0f : v;
    }
}

// ---------------- fallback path (ws too small) ----------------

__global__ void copy_kernel(const float4* __restrict__ X, float4* __restrict__ out,
                            int nvec, const float* __restrict__ Xs,
                            float* __restrict__ outs, int nscalar_base, int ntotal) {
    int i = blockIdx.x * blockDim.x + threadIdx.x;
    int stride = gridDim.x * blockDim.x;
    for (int j = i; j < nvec; j += stride) out[j] = X[j];
    int t = nscalar_base + i;
    if (t < ntotal) outs[t] = Xs[t];
}

__global__ void scatter_zero_kernel(const int* __restrict__ idx, int k,
                                    float* __restrict__ out) {
    int i = blockIdx.x * blockDim.x + threadIdx.x;
    int stride = gridDim.x * blockDim.x;
    for (; i < k; i += stride) out[idx[i]] = 0.0f;
}

extern "C" void kernel_launch(void* const* d_in, const int* in_sizes, int n_in,
                              void* d_out, int out_size, void* d_ws, size_t ws_size,
                              hipStream_t stream) {
    const float* X = (const float*)d_in[0];
    const int* drop_idx = (const int*)d_in[1];
    float* out = (float*)d_out;

    const int n = out_size;                 // 33,554,432
    const int k = in_sizes[1];              // ~10,066,329
    const int nvec = n >> 2;                // full float4s
    const int nscalar_base = nvec << 2;     // tail start
    const int nwords = (n + 31) >> 5;       // bitmask words
    const size_t mask_bytes = (size_t)nwords * sizeof(uint32_t);

    if (ws_size >= mask_bytes) {
        uint32_t* mask = (uint32_t*)d_ws;

        int blk_zero = (nwords + THREADS - 1) / THREADS;
        if (blk_zero > 1024) blk_zero = 1024;
        zero_mask_kernel<<<blk_zero, THREADS, 0, stream>>>(mask, nwords);

        int blk_set = (k + THREADS - 1) / THREADS;
        if (blk_set > 2048) blk_set = 2048;
        set_bits_kernel<<<blk_set, THREADS, 0, stream>>>(drop_idx, k, mask);

        int blk_apply = (nvec + THREADS - 1) / THREADS;
        if (blk_apply > 2048) blk_apply = 2048;
        apply_kernel<<<blk_apply, THREADS, 0, stream>>>(
            (const float4*)X, mask, (float4*)out, nvec,
            X, out, nscalar_base, n);
    } else {
        // fallback: plain copy then scatter zeros
        int blk_copy = (nvec + THREADS - 1) / THREADS;
        if (blk_copy > 2048) blk_copy = 2048;
        copy_kernel<<<blk_copy, THREADS, 0, stream>>>(
            (const float4*)X, (float4*)out, nvec, X, out, nscalar_base, n);
        int blk_set = (k + THREADS - 1) / THREADS;
        if (blk_set > 2048) blk_set = 2048;
        scatter_zero_kernel<<<blk_set, THREADS, 0, stream>>>(drop_idx, k, out);
    }
}

// Round 2
// 273.792 us; speedup vs baseline: 1.5862x; 1.5862x over previous
//
#include <hip/hip_runtime.h>
#include <stdint.h>

#define THREADS 256

// ---------------- byte-mask path (no atomics) ----------------

__global__ void zero_mask4_kernel(uint4* __restrict__ mask, int nquads) {
    int i = blockIdx.x * blockDim.x + threadIdx.x;
    int stride = gridDim.x * blockDim.x;
    uint4 z = make_uint4(0u, 0u, 0u, 0u);
    for (; i < nquads; i += stride) mask[i] = z;
}

__global__ void scatter_bytes_kernel(const int* __restrict__ idx, int k,
                                     uint8_t* __restrict__ mask) {
    int i = blockIdx.x * blockDim.x + threadIdx.x;
    int stride = gridDim.x * blockDim.x;
    for (; i < k; i += stride) {
        mask[(unsigned)idx[i]] = (uint8_t)1;
    }
}

__global__ void apply_bytes_kernel(const float4* __restrict__ X,
                                   const uint32_t* __restrict__ maskw,
                                   float4* __restrict__ out, int nvec) {
    int i = blockIdx.x * blockDim.x + threadIdx.x;
    int stride = gridDim.x * blockDim.x;
    for (int j = i; j < nvec; j += stride) {
        float4 v = X[j];
        uint32_t m = maskw[j];       // 4 mask bytes for this float4
        if (m & 0x000000FFu) v.x = 0.0f;
        if (m & 0x0000FF00u) v.y = 0.0f;
        if (m & 0x00FF0000u) v.z = 0.0f;
        if (m & 0xFF000000u) v.w = 0.0f;
        out[j] = v;
    }
}

// ---------------- bitmask-atomic fallback ----------------

__global__ void zero_mask_kernel(uint32_t* __restrict__ mask, int nwords) {
    int i = blockIdx.x * blockDim.x + threadIdx.x;
    int stride = gridDim.x * blockDim.x;
    for (; i < nwords; i += stride) mask[i] = 0u;
}

__global__ void set_bits_kernel(const int* __restrict__ idx, int k,
                                uint32_t* __restrict__ mask) {
    int i = blockIdx.x * blockDim.x + threadIdx.x;
    int stride = gridDim.x * blockDim.x;
    for (; i < k; i += stride) {
        unsigned v = (unsigned)idx[i];
        atomicOr(&mask[v >> 5], 1u << (v & 31u));
    }
}

__global__ void apply_bits_kernel(const float4* __restrict__ X,
                                  const uint32_t* __restrict__ mask,
                                  float4* __restrict__ out, int nvec) {
    int i = blockIdx.x * blockDim.x + threadIdx.x;
    int stride = gridDim.x * blockDim.x;
    for (int j = i; j < nvec; j += stride) {
        float4 v = X[j];
        unsigned base = (unsigned)j << 2;
        unsigned bits = (mask[base >> 5] >> (base & 31u)) & 0xFu;
        if (bits & 1u) v.x = 0.0f;
        if (bits & 2u) v.y = 0.0f;
        if (bits & 4u) v.z = 0.0f;
        if (bits & 8u) v.w = 0.0f;
        out[j] = v;
    }
}

// ---------------- last-resort: copy + scatter ----------------

__global__ void copy_kernel(const float4* __restrict__ X, float4* __restrict__ out,
                            int nvec) {
    int i = blockIdx.x * blockDim.x + threadIdx.x;
    int stride = gridDim.x * blockDim.x;
    for (int j = i; j < nvec; j += stride) out[j] = X[j];
}

__global__ void scatter_zero_kernel(const int* __restrict__ idx, int k,
                                    float* __restrict__ out) {
    int i = blockIdx.x * blockDim.x + threadIdx.x;
    int stride = gridDim.x * blockDim.x;
    for (; i < k; i += stride) out[idx[i]] = 0.0f;
}

extern "C" void kernel_launch(void* const* d_in, const int* in_sizes, int n_in,
                              void* d_out, int out_size, void* d_ws, size_t ws_size,
                              hipStream_t stream) {
    const float* X = (const float*)d_in[0];
    const int* drop_idx = (const int*)d_in[1];
    float* out = (float*)d_out;

    const int n = out_size;            // 33,554,432 (divisible by 32)
    const int k = in_sizes[1];         // ~10,066,329
    const int nvec = n >> 2;

    const size_t bytemask_bytes = (size_t)n;            // 33.5 MB
    const size_t bitmask_bytes = (size_t)((n + 31) >> 5) * 4;

    if (ws_size >= bytemask_bytes) {
        uint8_t* mask = (uint8_t*)d_ws;
        int nquads = n >> 4;           // uint4 granules

        zero_mask4_kernel<<<2048, THREADS, 0, stream>>>((uint4*)mask, nquads);
        scatter_bytes_kernel<<<2048, THREADS, 0, stream>>>(drop_idx, k, mask);
        apply_bytes_kernel<<<2048, THREADS, 0, stream>>>(
            (const float4*)X, (const uint32_t*)mask, (float4*)out, nvec);
    } else if (ws_size >= bitmask_bytes) {
        uint32_t* mask = (uint32_t*)d_ws;
        int nwords = (n + 31) >> 5;

        zero_mask_kernel<<<1024, THREADS, 0, stream>>>(mask, nwords);
        set_bits_kernel<<<2048, THREADS, 0, stream>>>(drop_idx, k, mask);
        apply_bits_kernel<<<2048, THREADS, 0, stream>>>(
            (const float4*)X, mask, (float4*)out, nvec);
    } else {
        copy_kernel<<<2048, THREADS, 0, stream>>>((const float4*)X, (float4*)out, nvec);
        scatter_zero_kernel<<<2048, THREADS, 0, stream>>>(drop_idx, k, out);
    }
}

// Round 3
// 159.028 us; speedup vs baseline: 2.7310x; 1.7217x over previous
//
#include <hip/hip_runtime.h>
#include <stdint.h>

#define THREADS 256

// ---------------- binning path ----------------
#define RB 16                      // log2(region size in elements)
#define REGION (1u << RB)          // 65536 elements per region
#define NBMAX 512                  // max regions supported by LDS stage
#define CAPL 40                    // LDS stage slots per region per tile
#define ATILE 8192                 // indices per tile
#define ABLOCKS 768
#define ATHREADS 256

__global__ void init_counts_kernel(uint32_t* __restrict__ gcount, int nwords) {
    int i = blockIdx.x * blockDim.x + threadIdx.x;
    if (i < nwords) gcount[i] = 0u;
}

__global__ __launch_bounds__(ATHREADS)
void bin_kernel(const int* __restrict__ idx, int k, int nb, int cap,
                uint16_t* __restrict__ bdata, uint32_t* __restrict__ gcount,
                uint32_t* __restrict__ ovf_cnt, uint32_t* __restrict__ ovf, int ocap) {
    __shared__ uint16_t stage[NBMAX * CAPL];   // 40 KB
    __shared__ uint32_t lcnt[NBMAX];           // 2 KB
    __shared__ uint32_t lbase[NBMAX];          // 2 KB
    const int ntiles = (k + ATILE - 1) / ATILE;
    for (int t = blockIdx.x; t < ntiles; t += gridDim.x) {
        for (int b = threadIdx.x; b < nb; b += ATHREADS) lcnt[b] = 0u;
        __syncthreads();
        const int base_i = t * ATILE;
        // phase 1: stage into LDS bins
        for (int j = threadIdx.x; j < ATILE; j += ATHREADS) {
            const int i = base_i + j;
            if (i < k) {
                const unsigned v = (unsigned)idx[i];
                const unsigned b = v >> RB;
                const unsigned off = v & (REGION - 1u);
                const unsigned lp = atomicAdd(&lcnt[b], 1u);
                if (lp < CAPL) {
                    stage[b * CAPL + lp] = (uint16_t)off;
                } else {               // stage overflow: direct global (rare)
                    const unsigned gp = atomicAdd(&gcount[b], 1u);
                    if (gp < (unsigned)cap) bdata[(size_t)b * cap + gp] = (uint16_t)off;
                    else {
                        const unsigned o = atomicAdd(ovf_cnt, 1u);
                        if (o < (unsigned)ocap) ovf[o] = v;
                    }
                }
            }
        }
        __syncthreads();
        // phase 2a: one global atomic per active region (parallel across threads)
        for (int b = threadIdx.x; b < nb; b += ATHREADS) {
            unsigned m = lcnt[b];
            if (m > CAPL) m = CAPL;
            lcnt[b] = m;
            lbase[b] = m ? atomicAdd(&gcount[b], m) : 0u;
        }
        __syncthreads();
        // phase 2b: flush staged entries (contiguous per region)
        for (int b = threadIdx.x; b < nb; b += ATHREADS) {
            const unsigned m = lcnt[b];
            const unsigned gb = lbase[b];
            for (unsigned j = 0; j < m; ++j) {
                const unsigned gp = gb + j;
                const uint16_t off = stage[b * CAPL + j];
                if (gp < (unsigned)cap) bdata[(size_t)b * cap + gp] = off;
                else {
                    const unsigned o = atomicAdd(ovf_cnt, 1u);
                    if (o < (unsigned)ocap) ovf[o] = ((unsigned)b << RB) | (unsigned)off;
                }
            }
        }
        __syncthreads();
    }
}

__global__ __launch_bounds__(512)
void apply_region_kernel(const float4* __restrict__ X, float4* __restrict__ out,
                         int nvec, int cap, const uint16_t* __restrict__ bdata,
                         const uint32_t* __restrict__ gcount) {
    __shared__ uint8_t lmask[REGION];          // 64 KB byte mask for this region
    const int b = blockIdx.x;
    uint4* lm4 = (uint4*)lmask;
    for (int j = threadIdx.x; j < (int)(REGION / 16); j += 512)
        lm4[j] = make_uint4(0u, 0u, 0u, 0u);
    __syncthreads();
    unsigned m = gcount[b];
    if (m > (unsigned)cap) m = (unsigned)cap;
    const uint16_t* bd = bdata + (size_t)b * cap;
    for (unsigned j = threadIdx.x; j < m; j += 512) lmask[bd[j]] = (uint8_t)1;
    __syncthreads();
    const uint32_t* lm32 = (const uint32_t*)lmask;
    const int rbase = b << (RB - 2);           // region base in float4 units
    for (int j = threadIdx.x; j < (int)(REGION / 4); j += 512) {
        const int g = rbase + j;
        if (g < nvec) {
            float4 v = X[g];
            const uint32_t mm = lm32[j];
            if (mm & 0x000000FFu) v.x = 0.0f;
            if (mm & 0x0000FF00u) v.y = 0.0f;
            if (mm & 0x00FF0000u) v.z = 0.0f;
            if (mm & 0xFF000000u) v.w = 0.0f;
            out[g] = v;
        }
    }
}

__global__ void ovf_scatter_kernel(const uint32_t* __restrict__ ovf_cnt,
                                   const uint32_t* __restrict__ ovf, int ocap,
                                   float* __restrict__ out) {
    unsigned c = *ovf_cnt;
    if (c > (unsigned)ocap) c = (unsigned)ocap;
    unsigned i = blockIdx.x * blockDim.x + threadIdx.x;
    const unsigned stride = gridDim.x * blockDim.x;
    for (; i < c; i += stride) out[ovf[i]] = 0.0f;
}

// ---------------- byte-mask fallback ----------------

__global__ void zero_mask4_kernel(uint4* __restrict__ mask, int nquads) {
    int i = blockIdx.x * blockDim.x + threadIdx.x;
    int stride = gridDim.x * blockDim.x;
    uint4 z = make_uint4(0u, 0u, 0u, 0u);
    for (; i < nquads; i += stride) mask[i] = z;
}

__global__ void scatter_bytes_kernel(const int* __restrict__ idx, int k,
                                     uint8_t* __restrict__ mask) {
    int i = blockIdx.x * blockDim.x + threadIdx.x;
    int stride = gridDim.x * blockDim.x;
    for (; i < k; i += stride) mask[(unsigned)idx[i]] = (uint8_t)1;
}

__global__ void apply_bytes_kernel(const float4* __restrict__ X,
                                   const uint32_t* __restrict__ maskw,
                                   float4* __restrict__ out, int nvec) {
    int i = blockIdx.x * blockDim.x + threadIdx.x;
    int stride = gridDim.x * blockDim.x;
    for (int j = i; j < nvec; j += stride) {
        float4 v = X[j];
        uint32_t m = maskw[j];
        if (m & 0x000000FFu) v.x = 0.0f;
        if (m & 0x0000FF00u) v.y = 0.0f;
        if (m & 0x00FF0000u) v.z = 0.0f;
        if (m & 0xFF000000u) v.w = 0.0f;
        out[j] = v;
    }
}

// ---------------- last-resort: copy + scatter ----------------

__global__ void copy_kernel(const float4* __restrict__ X, float4* __restrict__ out,
                            int nvec) {
    int i = blockIdx.x * blockDim.x + threadIdx.x;
    int stride = gridDim.x * blockDim.x;
    for (int j = i; j < nvec; j += stride) out[j] = X[j];
}

__global__ void scatter_zero_kernel(const int* __restrict__ idx, int k,
                                    float* __restrict__ out) {
    int i = blockIdx.x * blockDim.x + threadIdx.x;
    int stride = gridDim.x * blockDim.x;
    for (; i < k; i += stride) out[idx[i]] = 0.0f;
}

extern "C" void kernel_launch(void* const* d_in, const int* in_sizes, int n_in,
                              void* d_out, int out_size, void* d_ws, size_t ws_size,
                              hipStream_t stream) {
    const float* X = (const float*)d_in[0];
    const int* drop_idx = (const int*)d_in[1];
    float* out = (float*)d_out;

    const int n = out_size;            // 33,554,432
    const int k = in_sizes[1];         // ~10,066,329
    const int nvec = n >> 2;
    const int nb = (n + (int)REGION - 1) >> RB;   // 512 regions

    // --- try binning path ---
    bool bin_ok = (nb <= NBMAX) && ((n & 3) == 0);
    if (bin_ok) {
        const size_t gcount_words = (size_t)nb + 8;     // +slot for ovf_cnt
        const size_t gcount_bytes = gcount_words * 4;
        const size_t ovf_reserve = (size_t)1 << 20;     // 1 MB min overflow list
        if (ws_size > gcount_bytes + ovf_reserve + (size_t)nb * 2 * 1024) {
            size_t avail = ws_size - gcount_bytes - ovf_reserve;
            size_t cap_sz = avail / ((size_t)nb * 2);
            if (cap_sz > (size_t)REGION) cap_sz = (size_t)REGION;
            const long expected = (long)k / (nb > 0 ? nb : 1);
            if ((long)cap_sz >= expected + (expected >> 1) + 1024) {
                const int cap = (int)cap_sz;
                const size_t bdata_bytes = (size_t)nb * cap * 2;
                uint16_t* bdata = (uint16_t*)d_ws;
                uint32_t* gcount = (uint32_t*)((char*)d_ws + bdata_bytes);
                uint32_t* ovf_cnt = gcount + nb;
                uint32_t* ovf = gcount + gcount_words;
                const int ocap = (int)((ws_size - bdata_bytes - gcount_bytes) / 4);

                const int init_blk = (int)((gcount_words + THREADS - 1) / THREADS);
                init_counts_kernel<<<init_blk, THREADS, 0, stream>>>(gcount, (int)gcount_words);

                int ntiles = (k + ATILE - 1) / ATILE;
                int abl = ntiles < ABLOCKS ? (ntiles > 0 ? ntiles : 1) : ABLOCKS;
                bin_kernel<<<abl, ATHREADS, 0, stream>>>(
                    drop_idx, k, nb, cap, bdata, gcount, ovf_cnt, ovf, ocap);

                apply_region_kernel<<<nb, 512, 0, stream>>>(
                    (const float4*)X, (float4*)out, nvec, cap, bdata, gcount);

                ovf_scatter_kernel<<<64, THREADS, 0, stream>>>(ovf_cnt, ovf, ocap, out);
                return;
            }
        }
    }

    // --- byte-mask fallback ---
    if (ws_size >= (size_t)n && (n & 15) == 0) {
        uint8_t* mask = (uint8_t*)d_ws;
        zero_mask4_kernel<<<2048, THREADS, 0, stream>>>((uint4*)mask, n >> 4);
        scatter_bytes_kernel<<<2048, THREADS, 0, stream>>>(drop_idx, k, mask);
        apply_bytes_kernel<<<2048, THREADS, 0, stream>>>(
            (const float4*)X, (const uint32_t*)mask, (float4*)out, nvec);
        return;
    }

    // --- last resort ---
    copy_kernel<<<2048, THREADS, 0, stream>>>((const float4*)X, (float4*)out, nvec);
    scatter_zero_kernel<<<2048, THREADS, 0, stream>>>(drop_idx, k, out);
}

// Round 4
// 149.601 us; speedup vs baseline: 2.9030x; 1.0630x over previous
//
#include <hip/hip_runtime.h>
#include <stdint.h>

#define THREADS 256

// ---------------- fixed-layout binning path ----------------
#define RB 16
#define REGION 65536u
#define NB 512                    // regions (requires n == NB * REGION)
#define ATILE 16384               // indices per tile (one block per tile)
#define CAPL 48                   // slots per (tile, region); lambda=32, +2.8 sigma
#define LSTRIDE 50                // LDS stage stride (u16); 50 -> dword stride 25, coprime w/ 32 banks
#define BTHREADS 512

__global__ void init_ovf_kernel(uint32_t* __restrict__ ovf_cnt) {
    if (threadIdx.x == 0 && blockIdx.x == 0) *ovf_cnt = 0u;
}

__global__ __launch_bounds__(BTHREADS)
void bin_fixed_kernel(const int* __restrict__ idx, int k, int ntiles,
                      uint16_t* __restrict__ bdata, uint16_t* __restrict__ cnt,
                      uint32_t* __restrict__ ovf_cnt, uint32_t* __restrict__ ovf,
                      int ocap) {
    __shared__ uint16_t stage[NB * LSTRIDE];   // 51200 B
    __shared__ uint32_t lcnt[NB];              // 2048 B
    const int t = blockIdx.x;
    for (int b = threadIdx.x; b < NB; b += BTHREADS) lcnt[b] = 0u;
    __syncthreads();

    const int base = t * ATILE;
    const int lim = (k - base < ATILE) ? (k - base) : ATILE;
    if (lim == ATILE) {
        const int4* idx4 = (const int4*)(idx + base);
        for (int j = threadIdx.x; j < ATILE / 4; j += BTHREADS) {
            const int4 v4 = idx4[j];
            const int vs[4] = {v4.x, v4.y, v4.z, v4.w};
            #pragma unroll
            for (int e = 0; e < 4; ++e) {
                const unsigned v = (unsigned)vs[e];
                const unsigned b = v >> RB;
                const unsigned off = v & 0xFFFFu;
                const unsigned lp = atomicAdd(&lcnt[b], 1u);
                if (lp < CAPL) stage[b * LSTRIDE + lp] = (uint16_t)off;
                else {
                    const unsigned o = atomicAdd(ovf_cnt, 1u);
                    if (o < (unsigned)ocap) ovf[o] = v;
                }
            }
        }
    } else {
        for (int j = threadIdx.x; j < lim; j += BTHREADS) {
            const unsigned v = (unsigned)idx[base + j];
            const unsigned b = v >> RB;
            const unsigned off = v & 0xFFFFu;
            const unsigned lp = atomicAdd(&lcnt[b], 1u);
            if (lp < CAPL) stage[b * LSTRIDE + lp] = (uint16_t)off;
            else {
                const unsigned o = atomicAdd(ovf_cnt, 1u);
                if (o < (unsigned)ocap) ovf[o] = v;
            }
        }
    }
    __syncthreads();

    // coalesced cnt write: [tile][region] layout
    for (int b = threadIdx.x; b < NB; b += BTHREADS) {
        unsigned m = lcnt[b];
        if (m > CAPL) m = CAPL;
        cnt[(size_t)t * NB + b] = (uint16_t)m;
    }
    // wave-parallel flush: wave w owns regions [w*64, w*64+64)
    const int wid = threadIdx.x >> 6;
    const int lane = threadIdx.x & 63;
    for (int b = wid * 64; b < wid * 64 + 64; ++b) {
        unsigned m = lcnt[b];
        if (m > CAPL) m = CAPL;
        uint16_t* dst = bdata + ((size_t)b * ntiles + t) * CAPL;
        for (unsigned j = lane; j < m; j += 64) dst[j] = stage[b * LSTRIDE + j];
    }
}

__global__ __launch_bounds__(512)
void apply_fixed_kernel(const float4* __restrict__ X, float4* __restrict__ out,
                        int nvec, int ntiles,
                        const uint16_t* __restrict__ bdata,
                        const uint16_t* __restrict__ cnt) {
    __shared__ uint8_t lmask[REGION];          // 64 KB
    const int r = blockIdx.x;
    uint4* lm4 = (uint4*)lmask;
    for (int j = threadIdx.x; j < (int)(REGION / 16); j += 512)
        lm4[j] = make_uint4(0u, 0u, 0u, 0u);
    __syncthreads();
    const int wid = threadIdx.x >> 6;
    const int lane = threadIdx.x & 63;
    for (int t = wid; t < ntiles; t += 8) {
        const unsigned m = cnt[(size_t)t * NB + r];
        const uint16_t* bd = bdata + ((size_t)r * ntiles + t) * CAPL;
        for (unsigned j = lane; j < m; j += 64) lmask[bd[j]] = (uint8_t)1;
    }
    __syncthreads();
    const uint32_t* lm32 = (const uint32_t*)lmask;
    const int rbase = r << (RB - 2);
    for (int j = threadIdx.x; j < (int)(REGION / 4); j += 512) {
        const int g = rbase + j;
        if (g < nvec) {
            float4 v = X[g];
            const uint32_t mm = lm32[j];
            if (mm & 0x000000FFu) v.x = 0.0f;
            if (mm & 0x0000FF00u) v.y = 0.0f;
            if (mm & 0x00FF0000u) v.z = 0.0f;
            if (mm & 0xFF000000u) v.w = 0.0f;
            out[g] = v;
        }
    }
}

__global__ void ovf_scatter_kernel(const uint32_t* __restrict__ ovf_cnt,
                                   const uint32_t* __restrict__ ovf, int ocap,
                                   float* __restrict__ out) {
    unsigned c = *ovf_cnt;
    if (c > (unsigned)ocap) c = (unsigned)ocap;
    unsigned i = blockIdx.x * blockDim.x + threadIdx.x;
    const unsigned stride = gridDim.x * blockDim.x;
    for (; i < c; i += stride) out[ovf[i]] = 0.0f;
}

// ---------------- byte-mask fallback ----------------

__global__ void zero_mask4_kernel(uint4* __restrict__ mask, int nquads) {
    int i = blockIdx.x * blockDim.x + threadIdx.x;
    int stride = gridDim.x * blockDim.x;
    uint4 z = make_uint4(0u, 0u, 0u, 0u);
    for (; i < nquads; i += stride) mask[i] = z;
}

__global__ void scatter_bytes_kernel(const int* __restrict__ idx, int k,
                                     uint8_t* __restrict__ mask) {
    int i = blockIdx.x * blockDim.x + threadIdx.x;
    int stride = gridDim.x * blockDim.x;
    for (; i < k; i += stride) mask[(unsigned)idx[i]] = (uint8_t)1;
}

__global__ void apply_bytes_kernel(const float4* __restrict__ X,
                                   const uint32_t* __restrict__ maskw,
                                   float4* __restrict__ out, int nvec) {
    int i = blockIdx.x * blockDim.x + threadIdx.x;
    int stride = gridDim.x * blockDim.x;
    for (int j = i; j < nvec; j += stride) {
        float4 v = X[j];
        uint32_t m = maskw[j];
        if (m & 0x000000FFu) v.x = 0.0f;
        if (m & 0x0000FF00u) v.y = 0.0f;
        if (m & 0x00FF0000u) v.z = 0.0f;
        if (m & 0xFF000000u) v.w = 0.0f;
        out[j] = v;
    }
}

// ---------------- last-resort ----------------

__global__ void copy_kernel(const float4* __restrict__ X, float4* __restrict__ out,
                            int nvec) {
    int i = blockIdx.x * blockDim.x + threadIdx.x;
    int stride = gridDim.x * blockDim.x;
    for (int j = i; j < nvec; j += stride) out[j] = X[j];
}

__global__ void scatter_zero_kernel(const int* __restrict__ idx, int k,
                                    float* __restrict__ out) {
    int i = blockIdx.x * blockDim.x + threadIdx.x;
    int stride = gridDim.x * blockDim.x;
    for (; i < k; i += stride) out[idx[i]] = 0.0f;
}

extern "C" void kernel_launch(void* const* d_in, const int* in_sizes, int n_in,
                              void* d_out, int out_size, void* d_ws, size_t ws_size,
                              hipStream_t stream) {
    const float* X = (const float*)d_in[0];
    const int* drop_idx = (const int*)d_in[1];
    float* out = (float*)d_out;

    const int n = out_size;            // 33,554,432 = 512 * 65536
    const int k = in_sizes[1];         // ~10,066,329
    const int nvec = n >> 2;

    if ((unsigned)n == NB * REGION && k > 0) {
        const int ntiles = (k + ATILE - 1) / ATILE;      // 615
        const size_t bdata_bytes = (size_t)NB * ntiles * CAPL * 2;   // ~30.2 MB
        const size_t cnt_bytes = (size_t)ntiles * NB * 2;            // ~0.63 MB
        const size_t fixed_need = bdata_bytes + cnt_bytes + 64 * 1024;
        if (ws_size >= fixed_need) {
            uint16_t* bdata = (uint16_t*)d_ws;
            uint16_t* cnt = (uint16_t*)((char*)d_ws + bdata_bytes);
            uint32_t* ovf_cnt = (uint32_t*)((char*)d_ws + bdata_bytes + cnt_bytes);
            uint32_t* ovf = ovf_cnt + 4;
            const int ocap = (int)((ws_size - bdata_bytes - cnt_bytes - 16) / 4) - 8;

            init_ovf_kernel<<<1, 64, 0, stream>>>(ovf_cnt);
            bin_fixed_kernel<<<ntiles, BTHREADS, 0, stream>>>(
                drop_idx, k, ntiles, bdata, cnt, ovf_cnt, ovf, ocap);
            apply_fixed_kernel<<<NB, 512, 0, stream>>>(
                (const float4*)X, (float4*)out, nvec, ntiles, bdata, cnt);
            ovf_scatter_kernel<<<64, THREADS, 0, stream>>>(ovf_cnt, ovf, ocap, out);
            return;
        }
    }

    // --- byte-mask fallback ---
    if (ws_size >= (size_t)n && (n & 15) == 0) {
        uint8_t* mask = (uint8_t*)d_ws;
        zero_mask4_kernel<<<2048, THREADS, 0, stream>>>((uint4*)mask, n >> 4);
        scatter_bytes_kernel<<<2048, THREADS, 0, stream>>>(drop_idx, k, mask);
        apply_bytes_kernel<<<2048, THREADS, 0, stream>>>(
            (const float4*)X, (const uint32_t*)mask, (float4*)out, nvec);
        return;
    }

    // --- last resort ---
    copy_kernel<<<2048, THREADS, 0, stream>>>((const float4*)X, (float4*)out, nvec);
    scatter_zero_kernel<<<2048, THREADS, 0, stream>>>(drop_idx, k, out);
}

// Round 5
// 118.310 us; speedup vs baseline: 3.6708x; 1.2645x over previous
//
#include <hip/hip_runtime.h>
#include <stdint.h>

#define THREADS 256

// ---------------- fixed-layout binning path ----------------
#define RB 16
#define REGION 65536u
#define NB 512                    // regions (requires n == NB * REGION)
#define ATILE 16384               // indices per tile (one block per tile)
#define CAPL 48                   // slots per (tile, region); lambda=32, +2.8 sigma
#define LSTRIDE 50                // LDS stage stride (u16); dword stride 25, coprime w/ 32 banks
#define BTHREADS 512
#define HALF_ELEMS 32768          // elements per apply block (half region)
#define MAXTILES 768

__global__ void init_ovf_kernel(uint32_t* __restrict__ ovf_cnt) {
    if (threadIdx.x == 0 && blockIdx.x == 0) *ovf_cnt = 0u;
}

__global__ __launch_bounds__(BTHREADS)
void bin_fixed_kernel(const int* __restrict__ idx, int k, int ntiles,
                      uint16_t* __restrict__ bdata, uint16_t* __restrict__ cnt,
                      uint32_t* __restrict__ ovf_cnt, uint32_t* __restrict__ ovf,
                      int ocap) {
    __shared__ uint16_t stage[NB * LSTRIDE];   // 51200 B
    __shared__ uint32_t lcnt[NB];              // 2048 B
    const int t = blockIdx.x;
    for (int b = threadIdx.x; b < NB; b += BTHREADS) lcnt[b] = 0u;
    __syncthreads();

    const int base = t * ATILE;
    const int lim = (k - base < ATILE) ? (k - base) : ATILE;
    if (lim == ATILE) {
        const int4* idx4 = (const int4*)(idx + base);
        for (int j = threadIdx.x; j < ATILE / 4; j += BTHREADS) {
            const int4 v4 = idx4[j];
            const int vs[4] = {v4.x, v4.y, v4.z, v4.w};
            #pragma unroll
            for (int e = 0; e < 4; ++e) {
                const unsigned v = (unsigned)vs[e];
                const unsigned b = v >> RB;
                const unsigned off = v & 0xFFFFu;
                const unsigned lp = atomicAdd(&lcnt[b], 1u);
                if (lp < CAPL) stage[b * LSTRIDE + lp] = (uint16_t)off;
                else {
                    const unsigned o = atomicAdd(ovf_cnt, 1u);
                    if (o < (unsigned)ocap) ovf[o] = v;
                }
            }
        }
    } else {
        for (int j = threadIdx.x; j < lim; j += BTHREADS) {
            const unsigned v = (unsigned)idx[base + j];
            const unsigned b = v >> RB;
            const unsigned off = v & 0xFFFFu;
            const unsigned lp = atomicAdd(&lcnt[b], 1u);
            if (lp < CAPL) stage[b * LSTRIDE + lp] = (uint16_t)off;
            else {
                const unsigned o = atomicAdd(ovf_cnt, 1u);
                if (o < (unsigned)ocap) ovf[o] = v;
            }
        }
    }
    __syncthreads();

    // cnt layout [region][tile] so apply preloads coalesced
    for (int b = threadIdx.x; b < NB; b += BTHREADS) {
        unsigned m = lcnt[b];
        if (m > CAPL) m = CAPL;
        cnt[(size_t)b * ntiles + t] = (uint16_t)m;
    }
    // wave-parallel flush: wave w owns regions [w*64, w*64+64)
    const int wid = threadIdx.x >> 6;
    const int lane = threadIdx.x & 63;
    for (int b = wid * 64; b < wid * 64 + 64; ++b) {
        unsigned m = lcnt[b];
        if (m > CAPL) m = CAPL;
        uint16_t* dst = bdata + ((size_t)b * ntiles + t) * CAPL;
        for (unsigned j = lane; j < m; j += 64) dst[j] = stage[b * LSTRIDE + j];
    }
}

__global__ __launch_bounds__(512)
void apply_half_kernel(const float4* __restrict__ X, float4* __restrict__ out,
                       int ntiles, const uint16_t* __restrict__ bdata,
                       const uint16_t* __restrict__ cnt) {
    __shared__ uint8_t lmask[HALF_ELEMS];      // 32 KB
    __shared__ uint16_t cnt_s[MAXTILES];       // 1.5 KB
    const int r = blockIdx.x >> 1;
    const unsigned hbit = (blockIdx.x & 1) << 15;

    uint4* lm4 = (uint4*)lmask;
    for (int j = threadIdx.x; j < (int)(HALF_ELEMS / 16); j += 512)
        lm4[j] = make_uint4(0u, 0u, 0u, 0u);
    for (int t = threadIdx.x; t < ntiles; t += 512)
        cnt_s[t] = cnt[(size_t)r * ntiles + t];
    __syncthreads();

    // speculative full-width read of this region's entry lists; predicate scatter
    const uint32_t* bd32 = (const uint32_t*)(bdata + (size_t)r * ntiles * CAPL);
    const int npairs = ntiles * (CAPL / 2);
    for (int i = threadIdx.x; i < npairs; i += 512) {
        const uint32_t w = bd32[i];
        const unsigned t = (unsigned)i / (CAPL / 2);
        const unsigned sp = ((unsigned)i - t * (CAPL / 2)) * 2u;
        const unsigned m = cnt_s[t];
        const unsigned e0 = w & 0xFFFFu;
        const unsigned e1 = w >> 16;
        if (sp < m && (e0 & 0x8000u) == hbit) lmask[e0 & 0x7FFFu] = (uint8_t)1;
        if (sp + 1 < m && (e1 & 0x8000u) == hbit) lmask[e1 & 0x7FFFu] = (uint8_t)1;
    }
    __syncthreads();

    const uint32_t* lm32 = (const uint32_t*)lmask;
    const int base4 = (int)((unsigned)blockIdx.x << 13);   // 8192 float4 per block
    for (int j = threadIdx.x; j < (int)(HALF_ELEMS / 4); j += 512) {
        const int g = base4 + j;
        float4 v = X[g];
        const uint32_t mm = lm32[j];
        if (mm & 0x000000FFu) v.x = 0.0f;
        if (mm & 0x0000FF00u) v.y = 0.0f;
        if (mm & 0x00FF0000u) v.z = 0.0f;
        if (mm & 0xFF000000u) v.w = 0.0f;
        out[g] = v;
    }
}

__global__ void ovf_scatter_kernel(const uint32_t* __restrict__ ovf_cnt,
                                   const uint32_t* __restrict__ ovf, int ocap,
                                   float* __restrict__ out) {
    unsigned c = *ovf_cnt;
    if (c > (unsigned)ocap) c = (unsigned)ocap;
    unsigned i = blockIdx.x * blockDim.x + threadIdx.x;
    const unsigned stride = gridDim.x * blockDim.x;
    for (; i < c; i += stride) out[ovf[i]] = 0.0f;
}

// ---------------- byte-mask fallback ----------------

__global__ void zero_mask4_kernel(uint4* __restrict__ mask, int nquads) {
    int i = blockIdx.x * blockDim.x + threadIdx.x;
    int stride = gridDim.x * blockDim.x;
    uint4 z = make_uint4(0u, 0u, 0u, 0u);
    for (; i < nquads; i += stride) mask[i] = z;
}

__global__ void scatter_bytes_kernel(const int* __restrict__ idx, int k,
                                     uint8_t* __restrict__ mask) {
    int i = blockIdx.x * blockDim.x + threadIdx.x;
    int stride = gridDim.x * blockDim.x;
    for (; i < k; i += stride) mask[(unsigned)idx[i]] = (uint8_t)1;
}

__global__ void apply_bytes_kernel(const float4* __restrict__ X,
                                   const uint32_t* __restrict__ maskw,
                                   float4* __restrict__ out, int nvec) {
    int i = blockIdx.x * blockDim.x + threadIdx.x;
    int stride = gridDim.x * blockDim.x;
    for (int j = i; j < nvec; j += stride) {
        float4 v = X[j];
        uint32_t m = maskw[j];
        if (m & 0x000000FFu) v.x = 0.0f;
        if (m & 0x0000FF00u) v.y = 0.0f;
        if (m & 0x00FF0000u) v.z = 0.0f;
        if (m & 0xFF000000u) v.w = 0.0f;
        out[j] = v;
    }
}

// ---------------- last-resort ----------------

__global__ void copy_kernel(const float4* __restrict__ X, float4* __restrict__ out,
                            int nvec) {
    int i = blockIdx.x * blockDim.x + threadIdx.x;
    int stride = gridDim.x * blockDim.x;
    for (int j = i; j < nvec; j += stride) out[j] = X[j];
}

__global__ void scatter_zero_kernel(const int* __restrict__ idx, int k,
                                    float* __restrict__ out) {
    int i = blockIdx.x * blockDim.x + threadIdx.x;
    int stride = gridDim.x * blockDim.x;
    for (; i < k; i += stride) out[idx[i]] = 0.0f;
}

extern "C" void kernel_launch(void* const* d_in, const int* in_sizes, int n_in,
                              void* d_out, int out_size, void* d_ws, size_t ws_size,
                              hipStream_t stream) {
    const float* X = (const float*)d_in[0];
    const int* drop_idx = (const int*)d_in[1];
    float* out = (float*)d_out;

    const int n = out_size;            // 33,554,432 = 512 * 65536
    const int k = in_sizes[1];         // ~10,066,329
    const int nvec = n >> 2;

    if ((unsigned)n == NB * REGION && k > 0) {
        const int ntiles = (k + ATILE - 1) / ATILE;      // 615
        const size_t bdata_bytes = (size_t)NB * ntiles * CAPL * 2;   // ~30.2 MB
        const size_t cnt_bytes = (size_t)NB * ntiles * 2;            // ~0.63 MB
        const size_t fixed_need = bdata_bytes + cnt_bytes + 64 * 1024;
        if (ntiles <= MAXTILES && ws_size >= fixed_need) {
            uint16_t* bdata = (uint16_t*)d_ws;
            uint16_t* cnt = (uint16_t*)((char*)d_ws + bdata_bytes);
            uint32_t* ovf_cnt = (uint32_t*)((char*)d_ws + bdata_bytes + cnt_bytes);
            uint32_t* ovf = ovf_cnt + 4;
            const int ocap = (int)((ws_size - bdata_bytes - cnt_bytes - 16) / 4) - 8;

            init_ovf_kernel<<<1, 64, 0, stream>>>(ovf_cnt);
            bin_fixed_kernel<<<ntiles, BTHREADS, 0, stream>>>(
                drop_idx, k, ntiles, bdata, cnt, ovf_cnt, ovf, ocap);
            apply_half_kernel<<<NB * 2, 512, 0, stream>>>(
                (const float4*)X, (float4*)out, ntiles, bdata, cnt);
            ovf_scatter_kernel<<<64, THREADS, 0, stream>>>(ovf_cnt, ovf, ocap, out);
            return;
        }
    }

    // --- byte-mask fallback ---
    if (ws_size >= (size_t)n && (n & 15) == 0) {
        uint8_t* mask = (uint8_t*)d_ws;
        zero_mask4_kernel<<<2048, THREADS, 0, stream>>>((uint4*)mask, n >> 4);
        scatter_bytes_kernel<<<2048, THREADS, 0, stream>>>(drop_idx, k, mask);
        apply_bytes_kernel<<<2048, THREADS, 0, stream>>>(
            (const float4*)X, (const uint32_t*)mask, (float4*)out, nvec);
        return;
    }

    // --- last resort ---
    copy_kernel<<<2048, THREADS, 0, stream>>>((const float4*)X, (float4*)out, nvec);
    scatter_zero_kernel<<<2048, THREADS, 0, stream>>>(drop_idx, k, out);
}